// Round 1
// baseline (219.490 us; speedup 1.0000x reference)
//
#include <hip/hip_runtime.h>
#include <cmath>

// ---- problem dims ----
#define BQ 4
#define QL 1024
#define SL 4096
#define DM 256
#define NH 8
#define HD 32

typedef __attribute__((ext_vector_type(8))) short short8;
typedef __attribute__((ext_vector_type(4))) short short4v;
typedef __attribute__((ext_vector_type(4))) float f32x4;
typedef __attribute__((ext_vector_type(4))) unsigned int uint4v;

#define MFMA16(a, b, c) __builtin_amdgcn_mfma_f32_16x16x32_bf16((a), (b), (c), 0, 0, 0)

__device__ __forceinline__ short f2bf(float f) {
  union { float f; unsigned int u; } x; x.f = f;
  unsigned int r = x.u + 0x7FFFu + ((x.u >> 16) & 1u);  // RNE
  return (short)(r >> 16);
}

// ---------------------------------------------------------------------------
// Mask element-size detection: bool(1B) vs int32/float32(4B).
//   bool bytes are 0/1 at every offset -> bytes at %4!=0 are ~half nonzero.
//   int32 0/1: bytes at %4!=0 all zero.  float 0.0/1.0: some bytes 0x3F/0x80 (>1).
__global__ void detect_mask_kernel(const unsigned char* __restrict__ m,
                                   unsigned int* __restrict__ flags) {
  __shared__ int fA, fB;
  if (threadIdx.x == 0) { fA = 0; fB = 0; }
  __syncthreads();
  int a = 0, bb = 0;
  for (int i = threadIdx.x; i < 65536; i += 256) {
    unsigned char c = m[i];
    a |= (c > 1);
    bb |= (((i & 3) != 0) & (c != 0));
  }
  if (a) atomicOr(&fA, 1);
  if (bb) atomicOr(&fB, 1);
  __syncthreads();
  if (threadIdx.x == 0) flags[0] = (fA || !fB) ? 4u : 1u;
}

// ---------------------------------------------------------------------------
// LayerNorm of query rows -> bf16. One wave per row (4 rows/block).
__global__ __launch_bounds__(256) void ln_q_kernel(const float* __restrict__ x,
                                                   const float* __restrict__ gw,
                                                   const float* __restrict__ bw,
                                                   short* __restrict__ out) {
  const int lane = threadIdx.x & 63;
  const int row = blockIdx.x * 4 + (threadIdx.x >> 6);
  const float* xr = x + (size_t)row * DM;
  f32x4 v = *(const f32x4*)(xr + lane * 4);
  float s = v[0] + v[1] + v[2] + v[3];
  float s2 = v[0]*v[0] + v[1]*v[1] + v[2]*v[2] + v[3]*v[3];
#pragma unroll
  for (int m = 1; m < 64; m <<= 1) { s += __shfl_xor(s, m); s2 += __shfl_xor(s2, m); }
  const float mu = s * (1.0f / DM);
  const float var = s2 * (1.0f / DM) - mu * mu;
  const float inv = rsqrtf(var + 1e-5f);
  f32x4 gv = *(const f32x4*)(gw + lane * 4);
  f32x4 bv = *(const f32x4*)(bw + lane * 4);
  short4v o;
#pragma unroll
  for (int i = 0; i < 4; ++i) o[i] = f2bf((v[i] - mu) * inv * gv[i] + bv[i]);
  *(short4v*)(out + (size_t)row * DM + lane * 4) = o;
}

// ---------------------------------------------------------------------------
// GEMM: C[m,n] = sum_k A[m,k] * W[n,k]  (x @ W^T), K=N=256.
// BM=BN=BK=64, 4 waves (2x2), each wave 32x32 via 2x2x(2 ks) mfma_16x16x32_bf16.
// EPI: 0 = bf16 out scaled (q-proj), 1 = bf16 out (k/v), 2 = f32 out + bias + residual.
template <int AF32, int EPI>
__global__ __launch_bounds__(256) void gemm_bt(const void* __restrict__ Ap,
                                               const float* __restrict__ W,
                                               const float* __restrict__ bias,
                                               void* __restrict__ outp,
                                               const float* __restrict__ resid,
                                               float oscale) {
  __shared__ __align__(16) short As[64][72];  // +8 pad: 144B rows, conflict-free frags
  __shared__ __align__(16) short Bs[64][72];
  const int t = threadIdx.x;
  const int lane = t & 63, w = t >> 6;
  const int wm = w >> 1, wn = w & 1;
  const int g = lane >> 4, lr = lane & 15;
  const int m0 = blockIdx.x * 64, n0 = blockIdx.y * 64;
  f32x4 acc[2][2] = {};

  for (int k0 = 0; k0 < DM; k0 += 64) {
#pragma unroll
    for (int c = 0; c < 2; ++c) {
      const int idx = t * 2 + c;          // 512 16B-chunks: row 0..63, cc 0..7
      const int row = idx >> 3, cc = idx & 7;
      short8 sv;
      if (AF32) {
        const float* src = (const float*)Ap + (size_t)(m0 + row) * DM + k0 + cc * 8;
        f32x4 f0 = *(const f32x4*)src;
        f32x4 f1 = *(const f32x4*)(src + 4);
#pragma unroll
        for (int j = 0; j < 4; ++j) { sv[j] = f2bf(f0[j]); sv[4 + j] = f2bf(f1[j]); }
      } else {
        sv = *(const short8*)((const short*)Ap + (size_t)(m0 + row) * DM + k0 + cc * 8);
      }
      *(short8*)&As[row][cc * 8] = sv;
      const float* wsrc = W + (size_t)(n0 + row) * DM + k0 + cc * 8;
      f32x4 w0 = *(const f32x4*)wsrc;
      f32x4 w1 = *(const f32x4*)(wsrc + 4);
      short8 wv;
#pragma unroll
      for (int j = 0; j < 4; ++j) { wv[j] = f2bf(w0[j]); wv[4 + j] = f2bf(w1[j]); }
      *(short8*)&Bs[row][cc * 8] = wv;
    }
    __syncthreads();
#pragma unroll
    for (int ks = 0; ks < 2; ++ks) {
      short8 af[2], bfr[2];
#pragma unroll
      for (int i = 0; i < 2; ++i) af[i] = *(const short8*)&As[wm * 32 + i * 16 + lr][ks * 32 + g * 8];
#pragma unroll
      for (int j = 0; j < 2; ++j) bfr[j] = *(const short8*)&Bs[wn * 32 + j * 16 + lr][ks * 32 + g * 8];
#pragma unroll
      for (int i = 0; i < 2; ++i)
#pragma unroll
        for (int j = 0; j < 2; ++j) acc[i][j] = MFMA16(af[i], bfr[j], acc[i][j]);
    }
    __syncthreads();
  }
  // epilogue: C row = (lane>>4)*4 + reg, col = lane&15  [m89-verified]
#pragma unroll
  for (int i = 0; i < 2; ++i)
#pragma unroll
    for (int j = 0; j < 2; ++j)
#pragma unroll
      for (int r = 0; r < 4; ++r) {
        const int row = m0 + wm * 32 + i * 16 + g * 4 + r;
        const int col = n0 + wn * 32 + j * 16 + lr;
        const float v = acc[i][j][r] + bias[col];
        if (EPI == 0) {
          ((short*)outp)[(size_t)row * DM + col] = f2bf(v * oscale);
        } else if (EPI == 1) {
          ((short*)outp)[(size_t)row * DM + col] = f2bf(v);
        } else {
          ((float*)outp)[(size_t)row * DM + col] = v + resid[(size_t)row * DM + col];
        }
      }
}

// ---------------------------------------------------------------------------
// Flash attention. Grid (Q/64, H, B). 4 waves x 16 q-rows. SBLK=64, full HD=32 per mfma.
// q is pre-scaled by log2(e)/sqrt(HD) -> use exp2 throughout.
__global__ __launch_bounds__(256) void attn_kernel(const short* __restrict__ qb,
                                                   const short* __restrict__ kb,
                                                   const short* __restrict__ vb,
                                                   const void* __restrict__ maskp,
                                                   const unsigned int* __restrict__ flags,
                                                   short* __restrict__ ao) {
  __shared__ __align__(16) short Ks[64][40];          // [s][hd], 80B rows
  __shared__ __align__(16) short Vs[32][72];          // [hd][s] transposed, 144B rows
  __shared__ __align__(16) unsigned char Ms[64][80];  // mask bytes [q][s], 80B rows
  __shared__ __align__(16) short Ps[64][72];          // P bf16 [q][s], 144B rows

  const int t = threadIdx.x;
  const int lane = t & 63, w = t >> 6;
  const int g = lane >> 4, lr = lane & 15;
  const int q0 = blockIdx.x * 64;
  const int h = blockIdx.y, b = blockIdx.z;
  const bool mode4 = (flags[0] == 4u);

  // Q fragment (A operand): row = lane&15 within wave's 16 rows, k contiguous
  const short8 qf =
      *(const short8*)(qb + ((size_t)(b * QL + q0 + w * 16 + lr)) * DM + h * HD + g * 8);

  f32x4 Ov[2] = {};
  float mrow[4], lrow[4];
#pragma unroll
  for (int r = 0; r < 4; ++r) { mrow[r] = -3e38f; lrow[r] = 0.0f; }

  const size_t kvb = (size_t)b * SL * DM + h * HD;
  const int srow = t >> 2, scc = t & 3;

  for (int s0 = 0; s0 < SL; s0 += 64) {
    // --- stage K tile [64][32]
    {
      short8 kv = *(const short8*)(kb + kvb + (size_t)(s0 + srow) * DM + scc * 8);
      *(short8*)&Ks[srow][scc * 8] = kv;
    }
    // --- stage V tile transposed -> Vs[hd][s]
    {
      short8 vv = *(const short8*)(vb + kvb + (size_t)(s0 + srow) * DM + scc * 8);
#pragma unroll
      for (int j = 0; j < 8; ++j) Vs[scc * 8 + j][srow] = vv[j];
    }
    // --- stage mask tile as bytes
    {
      const size_t mrow0 = ((size_t)b * QL + q0 + srow) * SL + s0;
      if (mode4) {
        const unsigned int* mp = (const unsigned int*)maskp + mrow0 + scc * 16;
        uint4v pk;
#pragma unroll
        for (int q4 = 0; q4 < 4; ++q4) {
          uint4v dv = *(const uint4v*)(mp + q4 * 4);
          pk[q4] = (dv[0] ? 1u : 0u) | (dv[1] ? 0x100u : 0u) | (dv[2] ? 0x10000u : 0u) |
                   (dv[3] ? 0x1000000u : 0u);
        }
        *(uint4v*)&Ms[srow][scc * 16] = pk;
      } else {
        uint4v bv2 = *(const uint4v*)((const unsigned char*)maskp + mrow0 + scc * 16);
        *(uint4v*)&Ms[srow][scc * 16] = bv2;
      }
    }
    __syncthreads();

    // --- scores: S^ = q~ . k  (already in log2 domain)
    f32x4 sc[4];
#pragma unroll
    for (int f = 0; f < 4; ++f) {
      short8 kf = *(const short8*)&Ks[f * 16 + lr][g * 8];
      f32x4 z = {0.f, 0.f, 0.f, 0.f};
      sc[f] = MFMA16(qf, kf, z);
    }
    // --- mask + tile max
    float tmax[4];
#pragma unroll
    for (int r = 0; r < 4; ++r) tmax[r] = -3e38f;
#pragma unroll
    for (int f = 0; f < 4; ++f)
#pragma unroll
      for (int r = 0; r < 4; ++r) {
        const float v = Ms[w * 16 + g * 4 + r][f * 16 + lr] ? sc[f][r] : -1e30f;
        sc[f][r] = v;
        tmax[r] = fmaxf(tmax[r], v);
      }
#pragma unroll
    for (int m = 1; m < 16; m <<= 1)
#pragma unroll
      for (int r = 0; r < 4; ++r) tmax[r] = fmaxf(tmax[r], __shfl_xor(tmax[r], m));
    // --- online softmax update
    float corr[4];
#pragma unroll
    for (int r = 0; r < 4; ++r) {
      const float mn = fmaxf(mrow[r], tmax[r]);
      corr[r] = __builtin_amdgcn_exp2f(mrow[r] - mn);
      mrow[r] = mn;
    }
    float psum[4] = {0.f, 0.f, 0.f, 0.f};
#pragma unroll
    for (int f = 0; f < 4; ++f)
#pragma unroll
      for (int r = 0; r < 4; ++r) {
        const float p = __builtin_amdgcn_exp2f(sc[f][r] - mrow[r]);
        sc[f][r] = p;
        psum[r] += p;
      }
#pragma unroll
    for (int r = 0; r < 4; ++r) lrow[r] = lrow[r] * corr[r] + psum[r];
#pragma unroll
    for (int n = 0; n < 2; ++n)
#pragma unroll
      for (int r = 0; r < 4; ++r) Ov[n][r] *= corr[r];
    // --- P -> LDS (bf16), wave-private rows
#pragma unroll
    for (int f = 0; f < 4; ++f)
#pragma unroll
      for (int r = 0; r < 4; ++r) Ps[w * 16 + g * 4 + r][f * 16 + lr] = f2bf(sc[f][r]);
    // --- PV
#pragma unroll
    for (int ks = 0; ks < 2; ++ks) {
      short8 pf = *(const short8*)&Ps[w * 16 + lr][ks * 32 + g * 8];
#pragma unroll
      for (int n = 0; n < 2; ++n) {
        short8 vf = *(const short8*)&Vs[n * 16 + lr][ks * 32 + g * 8];
        Ov[n] = MFMA16(pf, vf, Ov[n]);
      }
    }
    __syncthreads();
  }
  // --- finalize: full row-sum of l, divide, store bf16
#pragma unroll
  for (int m = 1; m < 16; m <<= 1)
#pragma unroll
    for (int r = 0; r < 4; ++r) lrow[r] += __shfl_xor(lrow[r], m);
#pragma unroll
  for (int n = 0; n < 2; ++n)
#pragma unroll
    for (int r = 0; r < 4; ++r) {
      const float o = Ov[n][r] / lrow[r];
      const size_t row = (size_t)b * QL + q0 + w * 16 + g * 4 + r;
      ao[row * DM + h * HD + n * 16 + lr] = f2bf(o);
    }
}

// ---------------------------------------------------------------------------
extern "C" void kernel_launch(void* const* d_in, const int* in_sizes, int n_in,
                              void* d_out, int out_size, void* d_ws, size_t ws_size,
                              hipStream_t stream) {
  const float* query = (const float*)d_in[0];
  const float* key   = (const float*)d_in[1];
  const float* value = (const float*)d_in[2];
  const void*  mask  = d_in[3];
  const float* wq = (const float*)d_in[4];
  const float* bq = (const float*)d_in[5];
  const float* wk = (const float*)d_in[6];
  const float* bk = (const float*)d_in[7];
  const float* wv = (const float*)d_in[8];
  const float* bv = (const float*)d_in[9];
  const float* wo = (const float*)d_in[10];
  const float* bo = (const float*)d_in[11];
  const float* lng = (const float*)d_in[12];
  const float* lnb = (const float*)d_in[13];
  float* out = (float*)d_out;

  char* ws = (char*)d_ws;
  unsigned int* flags = (unsigned int*)ws;
  short* xln = (short*)(ws + 4096);                       // 2 MB
  short* qb  = (short*)(ws + 4096 + (2u << 20));          // 2 MB
  short* kb  = (short*)(ws + 4096 + (4u << 20));          // 8 MB
  short* vb  = (short*)(ws + 4096 + (12u << 20));         // 8 MB
  short* ao  = (short*)(ws + 4096 + (20u << 20));         // 2 MB

  const float qscale = (float)(1.4426950408889634 / sqrt((double)HD));  // log2(e)/sqrt(HD)

  detect_mask_kernel<<<1, 256, 0, stream>>>((const unsigned char*)mask, flags);
  ln_q_kernel<<<(BQ * QL) / 4, 256, 0, stream>>>(query, lng, lnb, xln);
  gemm_bt<0, 0><<<dim3((BQ * QL) / 64, DM / 64), 256, 0, stream>>>(xln, wq, bq, qb, nullptr, qscale);
  gemm_bt<1, 1><<<dim3((BQ * SL) / 64, DM / 64), 256, 0, stream>>>(key, wk, bk, kb, nullptr, 1.0f);
  gemm_bt<1, 1><<<dim3((BQ * SL) / 64, DM / 64), 256, 0, stream>>>(value, wv, bv, vb, nullptr, 1.0f);
  attn_kernel<<<dim3(QL / 64, NH, BQ), 256, 0, stream>>>(qb, kb, vb, mask, flags, ao);
  gemm_bt<0, 2><<<dim3((BQ * QL) / 64, DM / 64), 256, 0, stream>>>(ao, wo, bo, out, query, 1.0f);
}

// Round 2
// 167.597 us; speedup vs baseline: 1.3096x; 1.3096x over previous
//
#include <hip/hip_runtime.h>
#include <cmath>

// ---- problem dims ----
#define BQ 4
#define QL 1024
#define SL 4096
#define DM 256
#define NH 8
#define HD 32

typedef __attribute__((ext_vector_type(8))) short short8;
typedef __attribute__((ext_vector_type(4))) short short4v;
typedef __attribute__((ext_vector_type(4))) float f32x4;
typedef __attribute__((ext_vector_type(4))) unsigned int uint4v;
typedef unsigned long long u64;

#define MFMA16(a, b, c) __builtin_amdgcn_mfma_f32_16x16x32_bf16((a), (b), (c), 0, 0, 0)

__device__ __forceinline__ short f2bf(float f) {
  union { float f; unsigned int u; } x; x.f = f;
  unsigned int r = x.u + 0x7FFFu + ((x.u >> 16) & 1u);  // RNE
  return (short)(r >> 16);
}
__device__ __forceinline__ unsigned int fu(float f) {
  union { float f; unsigned int u; } x; x.f = f; return x.u;
}

// ---------------------------------------------------------------------------
// Mask element-size detection: bool(1B) vs int32/float32(4B).
__global__ void detect_mask_kernel(const unsigned char* __restrict__ m,
                                   unsigned int* __restrict__ flags) {
  __shared__ int fA, fB;
  if (threadIdx.x == 0) { fA = 0; fB = 0; }
  __syncthreads();
  int a = 0, bb = 0;
  for (int i = threadIdx.x; i < 65536; i += 256) {
    unsigned char c = m[i];
    a |= (c > 1);
    bb |= (((i & 3) != 0) & (c != 0));
  }
  if (a) atomicOr(&fA, 1);
  if (bb) atomicOr(&fB, 1);
  __syncthreads();
  if (threadIdx.x == 0) flags[0] = (fA || !fB) ? 4u : 1u;
}

// ---------------------------------------------------------------------------
// Pack mask into per-(q,sblock) 64-bit words via ballot. Bit s-local = lane.
// W[(b*QL+q)*64 + sb] bit i  <->  mask[b][q][sb*64+i]
__global__ __launch_bounds__(256) void maskbits_kernel(const void* __restrict__ mask,
                                                       const unsigned int* __restrict__ flags,
                                                       u64* __restrict__ W) {
  const int w = threadIdx.x >> 6, l = threadIdx.x & 63;
  const int row = blockIdx.x * 4 + w;  // b*QL + q
  u64* Wr = W + (size_t)row * 64;
  if (flags[0] == 4u) {
    const unsigned int* src = (const unsigned int*)mask + (size_t)row * SL;
    for (int sb = 0; sb < 64; ++sb) {
      u64 bal = __ballot(src[sb * 64 + l] != 0u);
      if (l == 0) Wr[sb] = bal;
    }
  } else {
    const unsigned char* src = (const unsigned char*)mask + (size_t)row * SL;
    for (int sb = 0; sb < 64; ++sb) {
      u64 bal = __ballot(src[sb * 64 + l] != 0);
      if (l == 0) Wr[sb] = bal;
    }
  }
}

// ---------------------------------------------------------------------------
// LayerNorm of query rows -> bf16. One wave per row (4 rows/block).
__global__ __launch_bounds__(256) void ln_q_kernel(const float* __restrict__ x,
                                                   const float* __restrict__ gw,
                                                   const float* __restrict__ bw,
                                                   short* __restrict__ out) {
  const int lane = threadIdx.x & 63;
  const int row = blockIdx.x * 4 + (threadIdx.x >> 6);
  const float* xr = x + (size_t)row * DM;
  f32x4 v = *(const f32x4*)(xr + lane * 4);
  float s = v[0] + v[1] + v[2] + v[3];
  float s2 = v[0]*v[0] + v[1]*v[1] + v[2]*v[2] + v[3]*v[3];
#pragma unroll
  for (int m = 1; m < 64; m <<= 1) { s += __shfl_xor(s, m); s2 += __shfl_xor(s2, m); }
  const float mu = s * (1.0f / DM);
  const float var = s2 * (1.0f / DM) - mu * mu;
  const float inv = rsqrtf(var + 1e-5f);
  f32x4 gv = *(const f32x4*)(gw + lane * 4);
  f32x4 bv = *(const f32x4*)(bw + lane * 4);
  short4v o;
#pragma unroll
  for (int i = 0; i < 4; ++i) o[i] = f2bf((v[i] - mu) * inv * gv[i] + bv[i]);
  *(short4v*)(out + (size_t)row * DM + lane * 4) = o;
}

// ---------------------------------------------------------------------------
// GEMM: C[m,n] = sum_k A[m,k] * W[n,k]  (x @ W^T), K=N=256.
// EPI: 0 = bf16 out scaled (q-proj), 1 = bf16 out (k), 2 = f32 out+bias+residual,
//      3 = bf16 transposed out [b][h][d][s] (v-proj).
template <int AF32, int EPI>
__global__ __launch_bounds__(256) void gemm_bt(const void* __restrict__ Ap,
                                               const float* __restrict__ W,
                                               const float* __restrict__ bias,
                                               void* __restrict__ outp,
                                               const float* __restrict__ resid,
                                               float oscale) {
  __shared__ __align__(16) short As[64][72];
  __shared__ __align__(16) short Bs[64][72];
  const int t = threadIdx.x;
  const int lane = t & 63, w = t >> 6;
  const int wm = w >> 1, wn = w & 1;
  const int g = lane >> 4, lr = lane & 15;
  const int m0 = blockIdx.x * 64, n0 = blockIdx.y * 64;
  f32x4 acc[2][2] = {};

  for (int k0 = 0; k0 < DM; k0 += 64) {
#pragma unroll
    for (int c = 0; c < 2; ++c) {
      const int idx = t * 2 + c;
      const int row = idx >> 3, cc = idx & 7;
      short8 sv;
      if (AF32) {
        const float* src = (const float*)Ap + (size_t)(m0 + row) * DM + k0 + cc * 8;
        f32x4 f0 = *(const f32x4*)src;
        f32x4 f1 = *(const f32x4*)(src + 4);
#pragma unroll
        for (int j = 0; j < 4; ++j) { sv[j] = f2bf(f0[j]); sv[4 + j] = f2bf(f1[j]); }
      } else {
        sv = *(const short8*)((const short*)Ap + (size_t)(m0 + row) * DM + k0 + cc * 8);
      }
      *(short8*)&As[row][cc * 8] = sv;
      const float* wsrc = W + (size_t)(n0 + row) * DM + k0 + cc * 8;
      f32x4 w0 = *(const f32x4*)wsrc;
      f32x4 w1 = *(const f32x4*)(wsrc + 4);
      short8 wv;
#pragma unroll
      for (int j = 0; j < 4; ++j) { wv[j] = f2bf(w0[j]); wv[4 + j] = f2bf(w1[j]); }
      *(short8*)&Bs[row][cc * 8] = wv;
    }
    __syncthreads();
#pragma unroll
    for (int ks = 0; ks < 2; ++ks) {
      short8 af[2], bfr[2];
#pragma unroll
      for (int i = 0; i < 2; ++i) af[i] = *(const short8*)&As[wm * 32 + i * 16 + lr][ks * 32 + g * 8];
#pragma unroll
      for (int j = 0; j < 2; ++j) bfr[j] = *(const short8*)&Bs[wn * 32 + j * 16 + lr][ks * 32 + g * 8];
#pragma unroll
      for (int i = 0; i < 2; ++i)
#pragma unroll
        for (int j = 0; j < 2; ++j) acc[i][j] = MFMA16(af[i], bfr[j], acc[i][j]);
    }
    __syncthreads();
  }
#pragma unroll
  for (int i = 0; i < 2; ++i)
#pragma unroll
    for (int j = 0; j < 2; ++j)
#pragma unroll
      for (int r = 0; r < 4; ++r) {
        const int row = m0 + wm * 32 + i * 16 + g * 4 + r;
        const int col = n0 + wn * 32 + j * 16 + lr;
        const float v = acc[i][j][r] + bias[col];
        if (EPI == 0) {
          ((short*)outp)[(size_t)row * DM + col] = f2bf(v * oscale);
        } else if (EPI == 1) {
          ((short*)outp)[(size_t)row * DM + col] = f2bf(v);
        } else if (EPI == 2) {
          ((float*)outp)[(size_t)row * DM + col] = v + resid[(size_t)row * DM + col];
        } else {
          // transposed: token row -> (b = row>>12, s = row&4095); col = h*32+hd
          ((short*)outp)[((size_t)(row >> 12) * DM + col) * SL + (row & (SL - 1))] = f2bf(v);
        }
      }
}

// ---------------------------------------------------------------------------
// Flash attention, swapped-QK^T formulation.
// Grid 512 blocks (XCD-swizzled). 4 waves x 16 q-rows. S-tile = 64.
// q pre-scaled by log2(e)/sqrt(HD) -> exp2 domain.
// Lane (g=l>>4, lr=l&15): QK phase holds S^T[s=f*16+g*4+r][q=lr];
// PV phase: A-frag = own packed P (k-permutation pi(ks,g,j)=(2ks+(j>>2))*16+g*4+(j&3)),
// B-frag = V^T rows d, read as 2x ds_read_b64 per (ks,n). C: q=g*4+r, d=n*16+lr.
__global__ __launch_bounds__(256) void attn_kernel(const short* __restrict__ qb,
                                                   const short* __restrict__ kb,
                                                   const short* __restrict__ vbT,
                                                   const u64* __restrict__ MW,
                                                   short* __restrict__ ao) {
  __shared__ __align__(16) short Ks[64][40];   // [s][hd] 80B rows
  __shared__ __align__(16) short Vs[32][76];   // [d][s]  152B rows

  // XCD swizzle: pin the 16 q-blocks of one (b,h) to a single XCD.
  const int n_ = blockIdx.x;
  const int x_ = n_ & 7, j_ = n_ >> 3;
  const int grp = ((j_ >> 4) << 3) + x_;       // 0..31 = h + 8*b
  const int q0 = (j_ & 15) * 64;
  const int h = grp & 7, b = grp >> 3;

  const int t = threadIdx.x;
  const int l = t & 63, w = t >> 6;
  const int g = l >> 4, lr = l & 15;

  const int srow = t >> 2, scc = t & 3;   // K staging: s=srow, hd-chunk scc*8
  const int vd = t >> 3, vsc = t & 7;     // V staging: d=vd, s-chunk vsc*8

  const short* Kp = kb + ((size_t)b * SL + srow) * DM + h * HD + scc * 8;
  const short* Vp = vbT + ((size_t)(b * NH + h) * HD + vd) * SL + vsc * 8;
  const u64* Wl = MW + ((size_t)(b * QL) + q0 + w * 16 + lr) * 64;

  const short8 qf =
      *(const short8*)(qb + ((size_t)(b * QL) + q0 + w * 16 + lr) * DM + h * HD + g * 8);

  f32x4 Ov[2] = {};
  float mcur = -1e30f, lsum = 0.0f;
  const int gsh = g * 4;

  // prologue: prefetch tile 0
  short8 kreg = *(const short8*)Kp;
  short8 vreg = *(const short8*)Vp;
  u64 mw = Wl[0];

  for (int it = 0; it < SL / 64; ++it) {
    __syncthreads();  // previous tile fully consumed
    *(short8*)&Ks[srow][scc * 8] = kreg;
    {  // two 8B writes (152B row stride keeps banks ~2-way)
      short4v lo = {vreg[0], vreg[1], vreg[2], vreg[3]};
      short4v hi = {vreg[4], vreg[5], vreg[6], vreg[7]};
      *(short4v*)&Vs[vd][vsc * 8] = lo;
      *(short4v*)&Vs[vd][vsc * 8 + 4] = hi;
    }
    __syncthreads();
    // prefetch next tile (latency hides under compute below)
    u64 mwn = 0;
    if (it < SL / 64 - 1) {
      kreg = *(const short8*)(Kp + (size_t)(it + 1) * 64 * DM);
      vreg = *(const short8*)(Vp + (it + 1) * 64);
      mwn = Wl[it + 1];
    }

    // --- QK^T (swapped): sc[f][r] = S^T[s=f*16+g*4+r][q=lr]
    f32x4 sc[4];
#pragma unroll
    for (int f = 0; f < 4; ++f) {
      short8 kf = *(const short8*)&Ks[f * 16 + lr][g * 8];
      f32x4 z = {0.f, 0.f, 0.f, 0.f};
      sc[f] = MFMA16(kf, qf, z);
    }
    // --- in-lane row max (16 values), then cross-g reduce
    float mx = sc[0][0];
#pragma unroll
    for (int f = 0; f < 4; ++f)
#pragma unroll
      for (int r = 0; r < 4; ++r) mx = fmaxf(mx, sc[f][r]);
    mx = fmaxf(mx, __shfl_xor(mx, 16));
    mx = fmaxf(mx, __shfl_xor(mx, 32));
    const float mnew = fmaxf(mcur, mx);
    const float corr = __builtin_amdgcn_exp2f(mcur - mnew);
    mcur = mnew;

    // --- p = exp2(s - m) * maskbit ; in-lane l accumulate; pack to bf16
    const unsigned int d0 = (unsigned int)mw, d1 = (unsigned int)(mw >> 32);
    unsigned int nib[4];
    nib[0] = d0 >> gsh; nib[1] = d0 >> (16 + gsh);
    nib[2] = d1 >> gsh; nib[3] = d1 >> (16 + gsh);
    float ls = 0.0f;
#pragma unroll
    for (int f = 0; f < 4; ++f)
#pragma unroll
      for (int r = 0; r < 4; ++r) {
        float p = __builtin_amdgcn_exp2f(sc[f][r] - mnew);
        p = ((nib[f] >> r) & 1u) ? p : 0.0f;
        sc[f][r] = p;
        ls += p;
      }
    lsum = lsum * corr + ls;
    unsigned int pk[4][2];
#pragma unroll
    for (int f = 0; f < 4; ++f) {
      pk[f][0] = (fu(sc[f][0]) >> 16) | (fu(sc[f][1]) & 0xFFFF0000u);
      pk[f][1] = (fu(sc[f][2]) >> 16) | (fu(sc[f][3]) & 0xFFFF0000u);
    }
    // --- rescale Ov by corr of its q-rows (q=g*4+r, pulled from lane g*4+r)
    float c4[4];
#pragma unroll
    for (int r = 0; r < 4; ++r) c4[r] = __shfl(corr, gsh + r);
#pragma unroll
    for (int n = 0; n < 2; ++n)
#pragma unroll
      for (int r = 0; r < 4; ++r) Ov[n][r] *= c4[r];
    // --- PV with k-permutation (A = own registers, zero shuffles)
#pragma unroll
    for (int ks = 0; ks < 2; ++ks) {
      union { unsigned int u[4]; short8 v; } pa;
      pa.u[0] = pk[2 * ks][0]; pa.u[1] = pk[2 * ks][1];
      pa.u[2] = pk[2 * ks + 1][0]; pa.u[3] = pk[2 * ks + 1][1];
#pragma unroll
      for (int n = 0; n < 2; ++n) {
        short4v va = *(const short4v*)&Vs[n * 16 + lr][(2 * ks) * 16 + gsh];
        short4v vb2 = *(const short4v*)&Vs[n * 16 + lr][(2 * ks + 1) * 16 + gsh];
        union { short4v h[2]; short8 v; } vf;
        vf.h[0] = va; vf.h[1] = vb2;
        Ov[n] = MFMA16(pa.v, vf.v, Ov[n]);
      }
    }
    mw = mwn;
  }
  // --- finalize: reduce l across g, redistribute to PV q-rows, divide, store
  lsum += __shfl_xor(lsum, 16);
  lsum += __shfl_xor(lsum, 32);
#pragma unroll
  for (int r = 0; r < 4; ++r) {
    const float lq = __shfl(lsum, gsh + r);
    const float rc = __builtin_amdgcn_rcpf(lq);
    const size_t row = (size_t)(b * QL) + q0 + w * 16 + gsh + r;
#pragma unroll
    for (int n = 0; n < 2; ++n)
      ao[row * DM + h * HD + n * 16 + lr] = f2bf(Ov[n][r] * rc);
  }
}

// ---------------------------------------------------------------------------
extern "C" void kernel_launch(void* const* d_in, const int* in_sizes, int n_in,
                              void* d_out, int out_size, void* d_ws, size_t ws_size,
                              hipStream_t stream) {
  const float* query = (const float*)d_in[0];
  const void*  mask  = d_in[3];
  const float* wq = (const float*)d_in[4];
  const float* bq = (const float*)d_in[5];
  const float* wk = (const float*)d_in[6];
  const float* bk = (const float*)d_in[7];
  const float* wv = (const float*)d_in[8];
  const float* bv = (const float*)d_in[9];
  const float* wo = (const float*)d_in[10];
  const float* bo = (const float*)d_in[11];
  const float* lng = (const float*)d_in[12];
  const float* lnb = (const float*)d_in[13];
  const float* key   = (const float*)d_in[1];
  const float* value = (const float*)d_in[2];
  float* out = (float*)d_out;

  char* ws = (char*)d_ws;
  unsigned int* flags = (unsigned int*)ws;
  short* xln = (short*)(ws + 4096);                 // 2 MB
  short* qb  = (short*)(ws + 4096 + (2u << 20));    // 2 MB
  short* kb  = (short*)(ws + 4096 + (4u << 20));    // 8 MB
  short* vbT = (short*)(ws + 4096 + (12u << 20));   // 8 MB (transposed [b][h][d][s])
  short* ao  = (short*)(ws + 4096 + (20u << 20));   // 2 MB
  u64*   mwd = (u64*)(ws + 4096 + (22u << 20));     // 2 MB

  const float qscale = (float)(1.4426950408889634 / sqrt((double)HD));

  detect_mask_kernel<<<1, 256, 0, stream>>>((const unsigned char*)mask, flags);
  maskbits_kernel<<<(BQ * QL) / 4, 256, 0, stream>>>(mask, flags, mwd);
  ln_q_kernel<<<(BQ * QL) / 4, 256, 0, stream>>>(query, lng, lnb, xln);
  gemm_bt<0, 0><<<dim3((BQ * QL) / 64, DM / 64), 256, 0, stream>>>(xln, wq, bq, qb, nullptr, qscale);
  gemm_bt<1, 1><<<dim3((BQ * SL) / 64, DM / 64), 256, 0, stream>>>(key, wk, bk, kb, nullptr, 1.0f);
  gemm_bt<1, 3><<<dim3((BQ * SL) / 64, DM / 64), 256, 0, stream>>>(value, wv, bv, vbT, nullptr, 1.0f);
  attn_kernel<<<512, 256, 0, stream>>>(qb, kb, vbT, mwd, ao);
  gemm_bt<0, 2><<<dim3((BQ * QL) / 64, DM / 64), 256, 0, stream>>>(ao, wo, bo, out, query, 1.0f);
}

// Round 3
// 148.977 us; speedup vs baseline: 1.4733x; 1.1250x over previous
//
#include <hip/hip_runtime.h>
#include <cmath>

// ---- problem dims ----
#define BQ 4
#define QL 1024
#define SL 4096
#define DM 256
#define NH 8
#define HD 32
#define NROWS 32768  // BQ*NH*QL

typedef __attribute__((ext_vector_type(8))) short short8;
typedef __attribute__((ext_vector_type(4))) short short4v;
typedef __attribute__((ext_vector_type(4))) float f32x4;
typedef __attribute__((ext_vector_type(4))) unsigned int uint4v;
typedef unsigned long long u64;

#define MFMA16(a, b, c) __builtin_amdgcn_mfma_f32_16x16x32_bf16((a), (b), (c), 0, 0, 0)

__device__ __forceinline__ short f2bf(float f) {
  union { float f; unsigned int u; } x; x.f = f;
  unsigned int r = x.u + 0x7FFFu + ((x.u >> 16) & 1u);  // RNE
  return (short)(r >> 16);
}
__device__ __forceinline__ unsigned int fu(float f) {
  union { float f; unsigned int u; } x; x.f = f; return x.u;
}
#define F3(a, b, c) fmaxf(fmaxf((a), (b)), (c))

// ---------------------------------------------------------------------------
// Convert key/value/weights f32 -> bf16 (RNE). Block 0 also runs mask detect.
#define CVT_CHUNKS 1081344  // (4194304*2 + 65536*4)/8
__global__ __launch_bounds__(256) void cvt_kernel(const float* __restrict__ key,
                                                  const float* __restrict__ value,
                                                  const float* __restrict__ wq,
                                                  const float* __restrict__ wk,
                                                  const float* __restrict__ wv,
                                                  const float* __restrict__ wo,
                                                  const unsigned char* __restrict__ mask,
                                                  unsigned int* __restrict__ flags,
                                                  short* __restrict__ kb16,
                                                  short* __restrict__ vb16,
                                                  short* __restrict__ w16) {
  if (blockIdx.x == 0) {
    __shared__ int fA, fB;
    if (threadIdx.x == 0) { fA = 0; fB = 0; }
    __syncthreads();
    int a = 0, bb = 0;
    for (int i = threadIdx.x; i < 65536; i += 256) {
      unsigned char c = mask[i];
      a |= (c > 1);
      bb |= (((i & 3) != 0) & (c != 0));
    }
    if (a) atomicOr(&fA, 1);
    if (bb) atomicOr(&fB, 1);
    __syncthreads();
    if (threadIdx.x == 0) flags[0] = (fA || !fB) ? 4u : 1u;
  }
  for (int i = blockIdx.x * 256 + threadIdx.x; i < CVT_CHUNKS; i += gridDim.x * 256) {
    const float* src;
    short* dst;
    if (i < 524288) {
      src = key + (size_t)i * 8; dst = kb16 + (size_t)i * 8;
    } else if (i < 1048576) {
      const int j = i - 524288;
      src = value + (size_t)j * 8; dst = vb16 + (size_t)j * 8;
    } else {
      int j = i - 1048576;
      if (j < 8192)       { src = wq + j * 8;            dst = w16 + j * 8; }
      else if (j < 16384) { src = wk + (j - 8192) * 8;   dst = w16 + 65536 + (j - 8192) * 8; }
      else if (j < 24576) { src = wv + (j - 16384) * 8;  dst = w16 + 131072 + (j - 16384) * 8; }
      else                { src = wo + (j - 24576) * 8;  dst = w16 + 196608 + (j - 24576) * 8; }
    }
    f32x4 a0 = *(const f32x4*)src;
    f32x4 a1 = *(const f32x4*)(src + 4);
    short8 o;
#pragma unroll
    for (int e = 0; e < 4; ++e) { o[e] = f2bf(a0[e]); o[4 + e] = f2bf(a1[e]); }
    *(short8*)dst = o;
  }
}

// ---------------------------------------------------------------------------
// Pack mask into per-(q,sblock) 64-bit words via ballot.
__global__ __launch_bounds__(256) void maskbits_kernel(const void* __restrict__ mask,
                                                       const unsigned int* __restrict__ flags,
                                                       u64* __restrict__ W) {
  const int w = threadIdx.x >> 6, l = threadIdx.x & 63;
  const int row = blockIdx.x * 4 + w;  // b*QL + q
  u64* Wr = W + (size_t)row * 64;
  if (flags[0] == 4u) {
    const unsigned int* src = (const unsigned int*)mask + (size_t)row * SL;
    for (int sb = 0; sb < 64; ++sb) {
      u64 bal = __ballot(src[sb * 64 + l] != 0u);
      if (l == 0) Wr[sb] = bal;
    }
  } else {
    const unsigned char* src = (const unsigned char*)mask + (size_t)row * SL;
    for (int sb = 0; sb < 64; ++sb) {
      u64 bal = __ballot(src[sb * 64 + l] != 0);
      if (l == 0) Wr[sb] = bal;
    }
  }
}

// ---------------------------------------------------------------------------
// LayerNorm of query rows -> bf16. One wave per row (4 rows/block).
__global__ __launch_bounds__(256) void ln_q_kernel(const float* __restrict__ x,
                                                   const float* __restrict__ gw,
                                                   const float* __restrict__ bw,
                                                   short* __restrict__ out) {
  const int lane = threadIdx.x & 63;
  const int row = blockIdx.x * 4 + (threadIdx.x >> 6);
  const float* xr = x + (size_t)row * DM;
  f32x4 v = *(const f32x4*)(xr + lane * 4);
  float s = v[0] + v[1] + v[2] + v[3];
  float s2 = v[0]*v[0] + v[1]*v[1] + v[2]*v[2] + v[3]*v[3];
#pragma unroll
  for (int m = 1; m < 64; m <<= 1) { s += __shfl_xor(s, m); s2 += __shfl_xor(s2, m); }
  const float mu = s * (1.0f / DM);
  const float var = s2 * (1.0f / DM) - mu * mu;
  const float inv = rsqrtf(var + 1e-5f);
  f32x4 gv = *(const f32x4*)(gw + lane * 4);
  f32x4 bv = *(const f32x4*)(bw + lane * 4);
  short4v o;
#pragma unroll
  for (int i = 0; i < 4; ++i) o[i] = f2bf((v[i] - mu) * inv * gv[i] + bv[i]);
  *(short4v*)(out + (size_t)row * DM + lane * 4) = o;
}

// ---------------------------------------------------------------------------
// GEMM: C[m,n] = sum_k A[m,k] * W[n,k], A and W bf16, K=N=256.
// EPI: 0 = bf16 out scaled (q-proj), 1 = bf16 out (k-proj),
//      2 = f32 out + bias + residual (out-proj),
//      3 = bf16 transposed out [b][d][s] (v-proj).
template <int EPI>
__global__ __launch_bounds__(256) void gemm_bt(const short* __restrict__ A,
                                               const short* __restrict__ W16,
                                               const float* __restrict__ bias,
                                               void* __restrict__ outp,
                                               const float* __restrict__ resid,
                                               float oscale) {
  __shared__ __align__(16) short As[64][72];
  __shared__ __align__(16) short Bs[64][72];
  const int t = threadIdx.x;
  const int lane = t & 63, w = t >> 6;
  const int wm = w >> 1, wn = w & 1;
  const int g = lane >> 4, lr = lane & 15, gsh = g * 4;
  const int m0 = blockIdx.x * 64, n0 = blockIdx.y * 64;
  const int row = (t * 2) >> 3, cc0 = (t * 2) & 7;  // two chunks: cc0, cc0+1
  f32x4 acc[2][2] = {};

  short8 an[2], bn[2];
#pragma unroll
  for (int c = 0; c < 2; ++c) {
    an[c] = *(const short8*)(A + (size_t)(m0 + row) * DM + (cc0 + c) * 8);
    bn[c] = *(const short8*)(W16 + (size_t)(n0 + row) * DM + (cc0 + c) * 8);
  }
  for (int k0 = 0; k0 < DM; k0 += 64) {
    if (k0) __syncthreads();
#pragma unroll
    for (int c = 0; c < 2; ++c) {
      *(short8*)&As[row][(cc0 + c) * 8] = an[c];
      *(short8*)&Bs[row][(cc0 + c) * 8] = bn[c];
    }
    __syncthreads();
    if (k0 < DM - 64) {
#pragma unroll
      for (int c = 0; c < 2; ++c) {
        an[c] = *(const short8*)(A + (size_t)(m0 + row) * DM + k0 + 64 + (cc0 + c) * 8);
        bn[c] = *(const short8*)(W16 + (size_t)(n0 + row) * DM + k0 + 64 + (cc0 + c) * 8);
      }
    }
#pragma unroll
    for (int ks = 0; ks < 2; ++ks) {
      short8 af[2], bfr[2];
#pragma unroll
      for (int i = 0; i < 2; ++i) af[i] = *(const short8*)&As[wm * 32 + i * 16 + lr][ks * 32 + g * 8];
#pragma unroll
      for (int j = 0; j < 2; ++j) bfr[j] = *(const short8*)&Bs[wn * 32 + j * 16 + lr][ks * 32 + g * 8];
#pragma unroll
      for (int i = 0; i < 2; ++i)
#pragma unroll
        for (int j = 0; j < 2; ++j) acc[i][j] = MFMA16(af[i], bfr[j], acc[i][j]);
    }
  }
  // C layout: row = g*4 + reg, col = lr [m89-verified]
  if (EPI == 2) {
#pragma unroll
    for (int i = 0; i < 2; ++i)
#pragma unroll
      for (int j = 0; j < 2; ++j)
#pragma unroll
        for (int r = 0; r < 4; ++r) {
          const int rr = m0 + wm * 32 + i * 16 + gsh + r;
          const int col = n0 + wn * 32 + j * 16 + lr;
          ((float*)outp)[(size_t)rr * DM + col] =
              acc[i][j][r] + bias[col] + resid[(size_t)rr * DM + col];
        }
  } else if (EPI == 0 || EPI == 1) {
    __syncthreads();  // LDS reuse for restage
#pragma unroll
    for (int i = 0; i < 2; ++i)
#pragma unroll
      for (int j = 0; j < 2; ++j) {
        const int nl = wn * 32 + j * 16 + lr;
        const float bv = bias[n0 + nl];
#pragma unroll
        for (int r = 0; r < 4; ++r)
          As[wm * 32 + i * 16 + gsh + r][nl] = f2bf((acc[i][j][r] + bv) * oscale);
      }
    __syncthreads();
#pragma unroll
    for (int c = 0; c < 2; ++c) {
      const int idx = t * 2 + c, dl = idx >> 3, ch = idx & 7;
      *(short8*)((short*)outp + (size_t)(m0 + dl) * DM + n0 + ch * 8) =
          *(const short8*)&As[dl][ch * 8];
    }
  } else {  // EPI == 3: transpose -> [b][d][s]
    __syncthreads();
#pragma unroll
    for (int i = 0; i < 2; ++i)
#pragma unroll
      for (int j = 0; j < 2; ++j) {
        const int nl = wn * 32 + j * 16 + lr;
        const float bv = bias[n0 + nl];
        short4v pk4;
#pragma unroll
        for (int r = 0; r < 4; ++r) pk4[r] = f2bf(acc[i][j][r] + bv);
        *(short4v*)&As[nl][wm * 32 + i * 16 + gsh] = pk4;
      }
    __syncthreads();
    const int bidx = m0 >> 12, sbase = m0 & (SL - 1);
#pragma unroll
    for (int c = 0; c < 2; ++c) {
      const int idx = t * 2 + c, dl = idx >> 3, ch = idx & 7;
      *(short8*)((short*)outp + ((size_t)bidx * DM + n0 + dl) * SL + sbase + ch * 8) =
          *(const short8*)&As[dl][ch * 8];
    }
  }
}

// ---------------------------------------------------------------------------
// Flash attention, swapped-QK^T, S-split in 2 halves. Grid 1024 (XCD-swizzled).
// Writes unnormalized partial O (f32), l, m per (half, row).
__global__ __launch_bounds__(256) void attn_kernel(const short* __restrict__ qb,
                                                   const short* __restrict__ kb,
                                                   const short* __restrict__ vbT,
                                                   const u64* __restrict__ MW,
                                                   float* __restrict__ Op,
                                                   float* __restrict__ Lp,
                                                   float* __restrict__ Mp) {
  __shared__ __align__(16) short Ks[64][40];   // [s][hd] 80B rows
  __shared__ __align__(16) short Vs[32][76];   // [d][s]  152B rows

  const int n_ = blockIdx.x;
  const int x_ = n_ & 7, j_ = n_ >> 3;
  const int grp = ((j_ >> 5) << 3) + x_;       // 0..31 = h + 8*b
  const int within = j_ & 31;
  const int q0 = (within & 15) * 64;
  const int half = within >> 4;
  const int h = grp & 7, b = grp >> 3;

  const int t = threadIdx.x;
  const int l = t & 63, w = t >> 6;
  const int g = l >> 4, lr = l & 15, gsh = g * 4;
  const int srow = t >> 2, scc = t & 3;
  const int vd = t >> 3, vsc = t & 7;

  const short* Kp = kb + ((size_t)b * SL + half * 2048 + srow) * DM + h * HD + scc * 8;
  const short* Vp = vbT + ((size_t)(b * NH + h) * HD + vd) * SL + half * 2048 + vsc * 8;
  const u64* Wl = MW + ((size_t)(b * QL) + q0 + w * 16 + lr) * 64 + half * 32;

  const short8 qf =
      *(const short8*)(qb + ((size_t)(b * QL) + q0 + w * 16 + lr) * DM + h * HD + g * 8);

  const short ONE = (short)0x3F80;
  const short8 ONES = {ONE, ONE, ONE, ONE, ONE, ONE, ONE, ONE};
  f32x4 Ov[2] = {};
  f32x4 Ls = {0.f, 0.f, 0.f, 0.f};
  float mcur = -1e30f;

  short8 kreg = *(const short8*)Kp;
  short8 vreg = *(const short8*)Vp;
  u64 mw = Wl[0];

  for (int it = 0; it < 32; ++it) {
    __syncthreads();
    *(short8*)&Ks[srow][scc * 8] = kreg;
    {
      short4v lo = {vreg[0], vreg[1], vreg[2], vreg[3]};
      short4v hi = {vreg[4], vreg[5], vreg[6], vreg[7]};
      *(short4v*)&Vs[vd][vsc * 8] = lo;
      *(short4v*)&Vs[vd][vsc * 8 + 4] = hi;
    }
    __syncthreads();
    u64 mwn = 0;
    if (it < 31) {
      kreg = *(const short8*)(Kp + (size_t)(it + 1) * 64 * DM);
      vreg = *(const short8*)(Vp + (it + 1) * 64);
      mwn = Wl[it + 1];
    }

    // --- QK^T (swapped): sc[f][r] = S^T[s=f*16+g*4+r][q=lr]
    f32x4 sc[4];
#pragma unroll
    for (int f = 0; f < 4; ++f) {
      short8 kf = *(const short8*)&Ks[f * 16 + lr][g * 8];
      f32x4 z = {0.f, 0.f, 0.f, 0.f};
      sc[f] = MFMA16(kf, qf, z);
    }
    // --- in-lane tile max (v_max3 tree), cross-g reduce
    float u0 = F3(sc[0][0], sc[0][1], sc[0][2]);
    float u1 = F3(sc[0][3], sc[1][0], sc[1][1]);
    float u2 = F3(sc[1][2], sc[1][3], sc[2][0]);
    float u3 = F3(sc[2][1], sc[2][2], sc[2][3]);
    float u4 = F3(sc[3][0], sc[3][1], sc[3][2]);
    float mx = fmaxf(F3(u0, u1, u2), F3(u3, u4, sc[3][3]));
    mx = fmaxf(mx, __shfl_xor(mx, 16));
    mx = fmaxf(mx, __shfl_xor(mx, 32));
    // --- defer-max: only rescale when tile max grew past threshold
    if (!__all(mx <= mcur + 8.0f)) {
      const float mnew = fmaxf(mcur, mx);
      const float corr = __builtin_amdgcn_exp2f(mcur - mnew);
      mcur = mnew;
      float c4[4];
#pragma unroll
      for (int r = 0; r < 4; ++r) c4[r] = __shfl(corr, gsh + r);
#pragma unroll
      for (int r = 0; r < 4; ++r) {
        Ov[0][r] *= c4[r];
        Ov[1][r] *= c4[r];
        Ls[r] *= c4[r];
      }
    }
    // --- p = exp2(s - m) * maskbit, pack pairs to bf16 via v_perm
    const unsigned int d0 = (unsigned int)mw, d1 = (unsigned int)(mw >> 32);
    unsigned int nib[4];
    nib[0] = d0 >> gsh; nib[1] = d0 >> (16 + gsh);
    nib[2] = d1 >> gsh; nib[3] = d1 >> (16 + gsh);
#pragma unroll
    for (int f = 0; f < 4; ++f)
#pragma unroll
      for (int r = 0; r < 4; ++r) {
        float p = __builtin_amdgcn_exp2f(sc[f][r] - mcur);
        sc[f][r] = ((nib[f] >> r) & 1u) ? p : 0.0f;
      }
    unsigned int pk[4][2];
#pragma unroll
    for (int f = 0; f < 4; ++f) {
      pk[f][0] = __builtin_amdgcn_perm(fu(sc[f][0]), fu(sc[f][1]), 0x03020706u);
      pk[f][1] = __builtin_amdgcn_perm(fu(sc[f][2]), fu(sc[f][3]), 0x03020706u);
    }
    // --- PV + row-sum via ones-MFMA (k-permutation: A = own registers)
#pragma unroll
    for (int ks = 0; ks < 2; ++ks) {
      union { unsigned int u[4]; short8 v; } pa;
      pa.u[0] = pk[2 * ks][0]; pa.u[1] = pk[2 * ks][1];
      pa.u[2] = pk[2 * ks + 1][0]; pa.u[3] = pk[2 * ks + 1][1];
      Ls = MFMA16(pa.v, ONES, Ls);
#pragma unroll
      for (int n = 0; n < 2; ++n) {
        short4v va = *(const short4v*)&Vs[n * 16 + lr][(2 * ks) * 16 + gsh];
        short4v vb2 = *(const short4v*)&Vs[n * 16 + lr][(2 * ks + 1) * 16 + gsh];
        union { short4v h[2]; short8 v; } vf;
        vf.h[0] = va; vf.h[1] = vb2;
        Ov[n] = MFMA16(pa.v, vf.v, Ov[n]);
      }
    }
    mw = mwn;
  }
  // --- write partials (unnormalized)
  const int ridx = (b * NH + h) * QL + q0 + w * 16;
  const size_t pb = (size_t)half * NROWS + ridx;
#pragma unroll
  for (int n = 0; n < 2; ++n)
#pragma unroll
    for (int r = 0; r < 4; ++r) Op[(pb + gsh + r) * 32 + n * 16 + lr] = Ov[n][r];
  if (lr == 0) {
#pragma unroll
    for (int r = 0; r < 4; ++r) Lp[pb + gsh + r] = Ls[r];
  }
  if (g == 0) Mp[pb + lr] = mcur;
}

// ---------------------------------------------------------------------------
// Merge the two S-halves: O = (O0*e^(m0-M) + O1*e^(m1-M)) / (l0*e^(m0-M)+l1*e^(m1-M))
__global__ __launch_bounds__(256) void combine_kernel(const float* __restrict__ Op,
                                                      const float* __restrict__ Lp,
                                                      const float* __restrict__ Mp,
                                                      short* __restrict__ ao) {
  const int tid = blockIdx.x * 256 + threadIdx.x;
  const int r = tid >> 3;
  const int dq = (tid & 7) * 4;
  const float m0 = Mp[r], m1 = Mp[NROWS + r];
  const float l0 = Lp[r], l1 = Lp[NROWS + r];
  const float M = fmaxf(m0, m1);
  const float a0 = __builtin_amdgcn_exp2f(m0 - M);
  const float a1 = __builtin_amdgcn_exp2f(m1 - M);
  const float inv = __builtin_amdgcn_rcpf(l0 * a0 + l1 * a1);
  const f32x4 o0 = *(const f32x4*)(Op + (size_t)r * 32 + dq);
  const f32x4 o1 = *(const f32x4*)(Op + ((size_t)NROWS + r) * 32 + dq);
  const int b = r >> 13, h = (r >> 10) & 7, q = r & 1023;
  short4v o;
#pragma unroll
  for (int i = 0; i < 4; ++i) o[i] = f2bf((o0[i] * a0 + o1[i] * a1) * inv);
  *(short4v*)(ao + ((size_t)(b * QL + q)) * DM + h * HD + dq) = o;
}

// ---------------------------------------------------------------------------
extern "C" void kernel_launch(void* const* d_in, const int* in_sizes, int n_in,
                              void* d_out, int out_size, void* d_ws, size_t ws_size,
                              hipStream_t stream) {
  const float* query = (const float*)d_in[0];
  const float* key   = (const float*)d_in[1];
  const float* value = (const float*)d_in[2];
  const void*  mask  = d_in[3];
  const float* wq = (const float*)d_in[4];
  const float* bq = (const float*)d_in[5];
  const float* wk = (const float*)d_in[6];
  const float* bk = (const float*)d_in[7];
  const float* wv = (const float*)d_in[8];
  const float* bv = (const float*)d_in[9];
  const float* wo = (const float*)d_in[10];
  const float* bo = (const float*)d_in[11];
  const float* lng = (const float*)d_in[12];
  const float* lnb = (const float*)d_in[13];
  float* out = (float*)d_out;

  char* ws = (char*)d_ws;
  unsigned int* flags = (unsigned int*)ws;
  short* xln = (short*)(ws + (1u << 20));    // 2 MB
  short* qb  = (short*)(ws + (3u << 20));    // 2 MB
  short* kb  = (short*)(ws + (5u << 20));    // 8 MB
  short* vbT = (short*)(ws + (13u << 20));   // 8 MB [b][d][s]
  u64*   mwd = (u64*)(ws + (21u << 20));     // 2 MB
  short* w16 = (short*)(ws + (23u << 20));   // 512 KB: wq,wk,wv,wo bf16
  char*  pool = ws + (24u << 20);            // 16 MB, time-shared:
  short* kb16 = (short*)pool;                //   bf16(key)   [dead after k-proj]
  short* vb16 = (short*)(pool + (8u << 20)); //   bf16(value) [dead after v-proj]
  float* Op = (float*)pool;                  //   8 MB partial O   [after v-proj]
  float* Lp = (float*)(pool + (8u << 20));              // 256 KB
  float* Mp = (float*)(pool + (8u << 20) + (256u << 10)); // 256 KB
  short* ao = (short*)(pool + (9u << 20));   //   2 MB

  const float qscale = (float)(1.4426950408889634 / sqrt((double)HD));

  cvt_kernel<<<2048, 256, 0, stream>>>(key, value, wq, wk, wv, wo,
                                       (const unsigned char*)mask, flags, kb16, vb16, w16);
  maskbits_kernel<<<(BQ * QL) / 4, 256, 0, stream>>>(mask, flags, mwd);
  ln_q_kernel<<<(BQ * QL) / 4, 256, 0, stream>>>(query, lng, lnb, xln);
  gemm_bt<0><<<dim3((BQ * QL) / 64, DM / 64), 256, 0, stream>>>(xln, w16, bq, qb, nullptr, qscale);
  gemm_bt<1><<<dim3((BQ * SL) / 64, DM / 64), 256, 0, stream>>>(kb16, w16 + 65536, bk, kb, nullptr, 1.0f);
  gemm_bt<3><<<dim3((BQ * SL) / 64, DM / 64), 256, 0, stream>>>(vb16, w16 + 131072, bv, vbT, nullptr, 1.0f);
  attn_kernel<<<1024, 256, 0, stream>>>(qb, kb, vbT, mwd, Op, Lp, Mp);
  combine_kernel<<<1024, 256, 0, stream>>>(Op, Lp, Mp, ao);
  gemm_bt<2><<<dim3((BQ * QL) / 64, DM / 64), 256, 0, stream>>>(ao, w16 + 196608, bo, out, query, 1.0f);
}

// Round 4
// 118.325 us; speedup vs baseline: 1.8550x; 1.2591x over previous
//
#include <hip/hip_runtime.h>
#include <cmath>

// ---- problem dims ----
#define BQ 4
#define QL 1024
#define SL 4096
#define DM 256
#define NH 8
#define HD 32
#define NROWS 32768   // BQ*NH*QL
#define NSPLIT 4      // attention S-splits
#define SEG (SL / NSPLIT)

typedef __attribute__((ext_vector_type(8))) short short8;
typedef __attribute__((ext_vector_type(4))) short short4v;
typedef __attribute__((ext_vector_type(4))) float f32x4;
typedef __attribute__((ext_vector_type(4))) unsigned int uint4v;
typedef unsigned long long u64;

#define MFMA16(a, b, c) __builtin_amdgcn_mfma_f32_16x16x32_bf16((a), (b), (c), 0, 0, 0)

__device__ __forceinline__ short f2bf(float f) {
  union { float f; unsigned int u; } x; x.f = f;
  unsigned int r = x.u + 0x7FFFu + ((x.u >> 16) & 1u);  // RNE
  return (short)(r >> 16);
}
__device__ __forceinline__ unsigned int fu(float f) {
  union { float f; unsigned int u; } x; x.f = f; return x.u;
}
#define F3(a, b, c) fmaxf(fmaxf((a), (b)), (c))

// ---------------------------------------------------------------------------
// Mask element-size detect, parallel: 1 block x 1024 threads, 64B/thread vectorized.
// byte>1 anywhere        -> w & 0xFEFEFEFE  (float-mode signature)
// nonzero byte at %4!=0  -> w & 0xFFFFFF00  (bool-mode signature)
// mode4 = fA || !fB  (int32 0/1 gives fA=0,fB=0 -> mode4; bool random -> fB=1 -> mode1)
__global__ __launch_bounds__(1024) void detect_kernel(const uint4v* __restrict__ m,
                                                      unsigned int* __restrict__ flags) {
  __shared__ int fA, fB;
  if (threadIdx.x == 0) { fA = 0; fB = 0; }
  __syncthreads();
  unsigned int a = 0, bb = 0;
#pragma unroll
  for (int i = 0; i < 4; ++i) {
    uint4v v = m[threadIdx.x * 4 + i];
#pragma unroll
    for (int e = 0; e < 4; ++e) {
      a |= (v[e] & 0xFEFEFEFEu);
      bb |= (v[e] & 0xFFFFFF00u);
    }
  }
  if (a) atomicOr(&fA, 1);
  if (bb) atomicOr(&fB, 1);
  __syncthreads();
  if (threadIdx.x == 0) flags[0] = (fA || !fB) ? 4u : 1u;
}

// ---------------------------------------------------------------------------
// Convert key/value/weights f32 -> bf16 (RNE). Pure streaming.
#define CVT_CHUNKS 1081344  // (4194304*2 + 65536*4)/8
__global__ __launch_bounds__(256) void cvt_kernel(const float* __restrict__ key,
                                                  const float* __restrict__ value,
                                                  const float* __restrict__ wq,
                                                  const float* __restrict__ wk,
                                                  const float* __restrict__ wv,
                                                  const float* __restrict__ wo,
                                                  short* __restrict__ kb16,
                                                  short* __restrict__ vb16,
                                                  short* __restrict__ w16) {
  for (int i = blockIdx.x * 256 + threadIdx.x; i < CVT_CHUNKS; i += gridDim.x * 256) {
    const float* src;
    short* dst;
    if (i < 524288) {
      src = key + (size_t)i * 8; dst = kb16 + (size_t)i * 8;
    } else if (i < 1048576) {
      const int j = i - 524288;
      src = value + (size_t)j * 8; dst = vb16 + (size_t)j * 8;
    } else {
      int j = i - 1048576;
      if (j < 8192)       { src = wq + j * 8;            dst = w16 + j * 8; }
      else if (j < 16384) { src = wk + (j - 8192) * 8;   dst = w16 + 65536 + (j - 8192) * 8; }
      else if (j < 24576) { src = wv + (j - 16384) * 8;  dst = w16 + 131072 + (j - 16384) * 8; }
      else                { src = wo + (j - 24576) * 8;  dst = w16 + 196608 + (j - 24576) * 8; }
    }
    f32x4 a0 = *(const f32x4*)src;
    f32x4 a1 = *(const f32x4*)(src + 4);
    short8 o;
#pragma unroll
    for (int e = 0; e < 4; ++e) { o[e] = f2bf(a0[e]); o[4 + e] = f2bf(a1[e]); }
    *(short8*)dst = o;
  }
}

// ---------------------------------------------------------------------------
// Pack mask into per-(q,sblock) 64-bit words via ballot.
__global__ __launch_bounds__(256) void maskbits_kernel(const void* __restrict__ mask,
                                                       const unsigned int* __restrict__ flags,
                                                       u64* __restrict__ W) {
  const int w = threadIdx.x >> 6, l = threadIdx.x & 63;
  const int row = blockIdx.x * 4 + w;  // b*QL + q
  u64* Wr = W + (size_t)row * 64;
  if (flags[0] == 4u) {
    const unsigned int* src = (const unsigned int*)mask + (size_t)row * SL;
    for (int sb = 0; sb < 64; ++sb) {
      u64 bal = __ballot(src[sb * 64 + l] != 0u);
      if (l == 0) Wr[sb] = bal;
    }
  } else {
    const unsigned char* src = (const unsigned char*)mask + (size_t)row * SL;
    for (int sb = 0; sb < 64; ++sb) {
      u64 bal = __ballot(src[sb * 64 + l] != 0);
      if (l == 0) Wr[sb] = bal;
    }
  }
}

// ---------------------------------------------------------------------------
// LayerNorm of query rows -> bf16. One wave per row (4 rows/block).
__global__ __launch_bounds__(256) void ln_q_kernel(const float* __restrict__ x,
                                                   const float* __restrict__ gw,
                                                   const float* __restrict__ bw,
                                                   short* __restrict__ out) {
  const int lane = threadIdx.x & 63;
  const int row = blockIdx.x * 4 + (threadIdx.x >> 6);
  const float* xr = x + (size_t)row * DM;
  f32x4 v = *(const f32x4*)(xr + lane * 4);
  float s = v[0] + v[1] + v[2] + v[3];
  float s2 = v[0]*v[0] + v[1]*v[1] + v[2]*v[2] + v[3]*v[3];
#pragma unroll
  for (int m = 1; m < 64; m <<= 1) { s += __shfl_xor(s, m); s2 += __shfl_xor(s2, m); }
  const float mu = s * (1.0f / DM);
  const float var = s2 * (1.0f / DM) - mu * mu;
  const float inv = rsqrtf(var + 1e-5f);
  f32x4 gv = *(const f32x4*)(gw + lane * 4);
  f32x4 bv = *(const f32x4*)(bw + lane * 4);
  short4v o;
#pragma unroll
  for (int i = 0; i < 4; ++i) o[i] = f2bf((v[i] - mu) * inv * gv[i] + bv[i]);
  *(short4v*)(out + (size_t)row * DM + lane * 4) = o;
}

// ---------------------------------------------------------------------------
// GEMM: C[m,n] = sum_k A[m,k] * W[n,k], A and W bf16, K=N=256.
// EPI: 0 = bf16 out scaled (q-proj), 1 = bf16 out (k-proj),
//      2 = f32 out + bias + residual (out-proj),
//      3 = bf16 transposed out [b][d][s] (v-proj).
template <int EPI>
__global__ __launch_bounds__(256) void gemm_bt(const short* __restrict__ A,
                                               const short* __restrict__ W16,
                                               const float* __restrict__ bias,
                                               void* __restrict__ outp,
                                               const float* __restrict__ resid,
                                               float oscale) {
  __shared__ __align__(16) short As[64][72];
  __shared__ __align__(16) short Bs[64][72];
  const int t = threadIdx.x;
  const int lane = t & 63, w = t >> 6;
  const int wm = w >> 1, wn = w & 1;
  const int g = lane >> 4, lr = lane & 15, gsh = g * 4;
  const int m0 = blockIdx.x * 64, n0 = blockIdx.y * 64;
  const int row = (t * 2) >> 3, cc0 = (t * 2) & 7;
  f32x4 acc[2][2] = {};

  short8 an[2], bn[2];
#pragma unroll
  for (int c = 0; c < 2; ++c) {
    an[c] = *(const short8*)(A + (size_t)(m0 + row) * DM + (cc0 + c) * 8);
    bn[c] = *(const short8*)(W16 + (size_t)(n0 + row) * DM + (cc0 + c) * 8);
  }
  for (int k0 = 0; k0 < DM; k0 += 64) {
    if (k0) __syncthreads();
#pragma unroll
    for (int c = 0; c < 2; ++c) {
      *(short8*)&As[row][(cc0 + c) * 8] = an[c];
      *(short8*)&Bs[row][(cc0 + c) * 8] = bn[c];
    }
    __syncthreads();
    if (k0 < DM - 64) {
#pragma unroll
      for (int c = 0; c < 2; ++c) {
        an[c] = *(const short8*)(A + (size_t)(m0 + row) * DM + k0 + 64 + (cc0 + c) * 8);
        bn[c] = *(const short8*)(W16 + (size_t)(n0 + row) * DM + k0 + 64 + (cc0 + c) * 8);
      }
    }
#pragma unroll
    for (int ks = 0; ks < 2; ++ks) {
      short8 af[2], bfr[2];
#pragma unroll
      for (int i = 0; i < 2; ++i) af[i] = *(const short8*)&As[wm * 32 + i * 16 + lr][ks * 32 + g * 8];
#pragma unroll
      for (int j = 0; j < 2; ++j) bfr[j] = *(const short8*)&Bs[wn * 32 + j * 16 + lr][ks * 32 + g * 8];
#pragma unroll
      for (int i = 0; i < 2; ++i)
#pragma unroll
        for (int j = 0; j < 2; ++j) acc[i][j] = MFMA16(af[i], bfr[j], acc[i][j]);
    }
  }
  // C layout: row = g*4 + reg, col = lr [m89-verified]
  if (EPI == 2) {
#pragma unroll
    for (int i = 0; i < 2; ++i)
#pragma unroll
      for (int j = 0; j < 2; ++j)
#pragma unroll
        for (int r = 0; r < 4; ++r) {
          const int rr = m0 + wm * 32 + i * 16 + gsh + r;
          const int col = n0 + wn * 32 + j * 16 + lr;
          ((float*)outp)[(size_t)rr * DM + col] =
              acc[i][j][r] + bias[col] + resid[(size_t)rr * DM + col];
        }
  } else if (EPI == 0 || EPI == 1) {
    __syncthreads();
#pragma unroll
    for (int i = 0; i < 2; ++i)
#pragma unroll
      for (int j = 0; j < 2; ++j) {
        const int nl = wn * 32 + j * 16 + lr;
        const float bv = bias[n0 + nl];
#pragma unroll
        for (int r = 0; r < 4; ++r)
          As[wm * 32 + i * 16 + gsh + r][nl] = f2bf((acc[i][j][r] + bv) * oscale);
      }
    __syncthreads();
#pragma unroll
    for (int c = 0; c < 2; ++c) {
      const int idx = t * 2 + c, dl = idx >> 3, ch = idx & 7;
      *(short8*)((short*)outp + (size_t)(m0 + dl) * DM + n0 + ch * 8) =
          *(const short8*)&As[dl][ch * 8];
    }
  } else {  // EPI == 3: transpose -> [b][d][s]
    __syncthreads();
#pragma unroll
    for (int i = 0; i < 2; ++i)
#pragma unroll
      for (int j = 0; j < 2; ++j) {
        const int nl = wn * 32 + j * 16 + lr;
        const float bv = bias[n0 + nl];
        short4v pk4;
#pragma unroll
        for (int r = 0; r < 4; ++r) pk4[r] = f2bf(acc[i][j][r] + bv);
        *(short4v*)&As[nl][wm * 32 + i * 16 + gsh] = pk4;
      }
    __syncthreads();
    const int bidx = m0 >> 12, sbase = m0 & (SL - 1);
#pragma unroll
    for (int c = 0; c < 2; ++c) {
      const int idx = t * 2 + c, dl = idx >> 3, ch = idx & 7;
      *(short8*)((short*)outp + ((size_t)bidx * DM + n0 + dl) * SL + sbase + ch * 8) =
          *(const short8*)&As[dl][ch * 8];
    }
  }
}

// ---------------------------------------------------------------------------
// Flash attention, swapped-QK^T, S-split in 4 quarters. Grid 2048 (XCD-swizzled,
// 8 blocks/CU). Writes unnormalized partial O (f32), l, m per (quarter, row).
__global__ __launch_bounds__(256) void attn_kernel(const short* __restrict__ qb,
                                                   const short* __restrict__ kb,
                                                   const short* __restrict__ vbT,
                                                   const u64* __restrict__ MW,
                                                   float* __restrict__ Op,
                                                   float* __restrict__ Lp,
                                                   float* __restrict__ Mp) {
  __shared__ __align__(16) short Ks[64][40];   // [s][hd] 80B rows
  __shared__ __align__(16) short Vs[32][76];   // [d][s]  152B rows

  // 32 groups (b,h) x 64 blocks (16 q0 x 4 quarters); group pinned to XCD grp&7.
  const int n_ = blockIdx.x;
  const int x_ = n_ & 7, j_ = n_ >> 3;         // j_: 0..255
  const int grp = ((j_ >> 6) << 3) + x_;       // 0..31 = h + 8*b
  const int within = j_ & 63;
  const int q0 = (within & 15) * 64;
  const int quarter = within >> 4;
  const int h = grp & 7, b = grp >> 3;

  const int t = threadIdx.x;
  const int l = t & 63, w = t >> 6;
  const int g = l >> 4, lr = l & 15, gsh = g * 4;
  const int srow = t >> 2, scc = t & 3;
  const int vd = t >> 3, vsc = t & 7;

  const short* Kp = kb + ((size_t)b * SL + quarter * SEG + srow) * DM + h * HD + scc * 8;
  const short* Vp = vbT + ((size_t)(b * NH + h) * HD + vd) * SL + quarter * SEG + vsc * 8;
  const u64* Wl = MW + ((size_t)(b * QL) + q0 + w * 16 + lr) * 64 + quarter * (SEG / 64);

  const short8 qf =
      *(const short8*)(qb + ((size_t)(b * QL) + q0 + w * 16 + lr) * DM + h * HD + g * 8);

  const short ONE = (short)0x3F80;
  const short8 ONES = {ONE, ONE, ONE, ONE, ONE, ONE, ONE, ONE};
  f32x4 Ov[2] = {};
  f32x4 Ls = {0.f, 0.f, 0.f, 0.f};
  float mcur = -1e30f;

  short8 kreg = *(const short8*)Kp;
  short8 vreg = *(const short8*)Vp;
  u64 mw = Wl[0];

  for (int it = 0; it < SEG / 64; ++it) {
    __syncthreads();
    *(short8*)&Ks[srow][scc * 8] = kreg;
    {
      short4v lo = {vreg[0], vreg[1], vreg[2], vreg[3]};
      short4v hi = {vreg[4], vreg[5], vreg[6], vreg[7]};
      *(short4v*)&Vs[vd][vsc * 8] = lo;
      *(short4v*)&Vs[vd][vsc * 8 + 4] = hi;
    }
    __syncthreads();
    u64 mwn = 0;
    if (it < SEG / 64 - 1) {
      kreg = *(const short8*)(Kp + (size_t)(it + 1) * 64 * DM);
      vreg = *(const short8*)(Vp + (it + 1) * 64);
      mwn = Wl[it + 1];
    }

    // --- QK^T (swapped): sc[f][r] = S^T[s=f*16+g*4+r][q=lr]
    f32x4 sc[4];
#pragma unroll
    for (int f = 0; f < 4; ++f) {
      short8 kf = *(const short8*)&Ks[f * 16 + lr][g * 8];
      f32x4 z = {0.f, 0.f, 0.f, 0.f};
      sc[f] = MFMA16(kf, qf, z);
    }
    // --- in-lane tile max (v_max3 tree), cross-g reduce
    float u0 = F3(sc[0][0], sc[0][1], sc[0][2]);
    float u1 = F3(sc[0][3], sc[1][0], sc[1][1]);
    float u2 = F3(sc[1][2], sc[1][3], sc[2][0]);
    float u3 = F3(sc[2][1], sc[2][2], sc[2][3]);
    float u4 = F3(sc[3][0], sc[3][1], sc[3][2]);
    float mx = fmaxf(F3(u0, u1, u2), F3(u3, u4, sc[3][3]));
    mx = fmaxf(mx, __shfl_xor(mx, 16));
    mx = fmaxf(mx, __shfl_xor(mx, 32));
    // --- defer-max: only rescale when tile max grew past threshold
    if (!__all(mx <= mcur + 8.0f)) {
      const float mnew = fmaxf(mcur, mx);
      const float corr = __builtin_amdgcn_exp2f(mcur - mnew);
      mcur = mnew;
      float c4[4];
#pragma unroll
      for (int r = 0; r < 4; ++r) c4[r] = __shfl(corr, gsh + r);
#pragma unroll
      for (int r = 0; r < 4; ++r) {
        Ov[0][r] *= c4[r];
        Ov[1][r] *= c4[r];
        Ls[r] *= c4[r];
      }
    }
    // --- p = exp2(s - m) * maskbit, pack pairs to bf16 via v_perm
    const unsigned int d0 = (unsigned int)mw, d1 = (unsigned int)(mw >> 32);
    unsigned int nib[4];
    nib[0] = d0 >> gsh; nib[1] = d0 >> (16 + gsh);
    nib[2] = d1 >> gsh; nib[3] = d1 >> (16 + gsh);
#pragma unroll
    for (int f = 0; f < 4; ++f)
#pragma unroll
      for (int r = 0; r < 4; ++r) {
        float p = __builtin_amdgcn_exp2f(sc[f][r] - mcur);
        sc[f][r] = ((nib[f] >> r) & 1u) ? p : 0.0f;
      }
    unsigned int pk[4][2];
#pragma unroll
    for (int f = 0; f < 4; ++f) {
      pk[f][0] = __builtin_amdgcn_perm(fu(sc[f][0]), fu(sc[f][1]), 0x03020706u);
      pk[f][1] = __builtin_amdgcn_perm(fu(sc[f][2]), fu(sc[f][3]), 0x03020706u);
    }
    // --- PV + row-sum via ones-MFMA (k-permutation: A = own registers)
#pragma unroll
    for (int ks = 0; ks < 2; ++ks) {
      union { unsigned int u[4]; short8 v; } pa;
      pa.u[0] = pk[2 * ks][0]; pa.u[1] = pk[2 * ks][1];
      pa.u[2] = pk[2 * ks + 1][0]; pa.u[3] = pk[2 * ks + 1][1];
      Ls = MFMA16(pa.v, ONES, Ls);
#pragma unroll
      for (int n = 0; n < 2; ++n) {
        short4v va = *(const short4v*)&Vs[n * 16 + lr][(2 * ks) * 16 + gsh];
        short4v vb2 = *(const short4v*)&Vs[n * 16 + lr][(2 * ks + 1) * 16 + gsh];
        union { short4v h[2]; short8 v; } vf;
        vf.h[0] = va; vf.h[1] = vb2;
        Ov[n] = MFMA16(pa.v, vf.v, Ov[n]);
      }
    }
    mw = mwn;
  }
  // --- write partials (unnormalized)
  const int ridx = (b * NH + h) * QL + q0 + w * 16;
  const size_t pb = (size_t)quarter * NROWS + ridx;
#pragma unroll
  for (int n = 0; n < 2; ++n)
#pragma unroll
    for (int r = 0; r < 4; ++r) Op[(pb + gsh + r) * 32 + n * 16 + lr] = Ov[n][r];
  if (lr == 0) {
#pragma unroll
    for (int r = 0; r < 4; ++r) Lp[pb + gsh + r] = Ls[r];
  }
  if (g == 0) Mp[pb + lr] = mcur;
}

// ---------------------------------------------------------------------------
// Merge NSPLIT partials: O = sum_i O_i e^(m_i-M) / sum_i l_i e^(m_i-M)
__global__ __launch_bounds__(256) void combine_kernel(const float* __restrict__ Op,
                                                      const float* __restrict__ Lp,
                                                      const float* __restrict__ Mp,
                                                      short* __restrict__ ao) {
  const int tid = blockIdx.x * 256 + threadIdx.x;
  const int r = tid >> 3;
  const int dq = (tid & 7) * 4;
  float m[NSPLIT], lv[NSPLIT];
  float M = -3e38f;
#pragma unroll
  for (int i = 0; i < NSPLIT; ++i) {
    m[i] = Mp[(size_t)i * NROWS + r];
    lv[i] = Lp[(size_t)i * NROWS + r];
    M = fmaxf(M, m[i]);
  }
  float den = 0.0f;
  f32x4 acc = {0.f, 0.f, 0.f, 0.f};
#pragma unroll
  for (int i = 0; i < NSPLIT; ++i) {
    const float a = __builtin_amdgcn_exp2f(m[i] - M);
    den += lv[i] * a;
    const f32x4 o = *(const f32x4*)(Op + ((size_t)i * NROWS + r) * 32 + dq);
#pragma unroll
    for (int e = 0; e < 4; ++e) acc[e] += o[e] * a;
  }
  const float inv = __builtin_amdgcn_rcpf(den);
  const int b = r >> 13, h = (r >> 10) & 7, q = r & 1023;
  short4v o;
#pragma unroll
  for (int i = 0; i < 4; ++i) o[i] = f2bf(acc[i] * inv);
  *(short4v*)(ao + ((size_t)(b * QL + q)) * DM + h * HD + dq) = o;
}

// ---------------------------------------------------------------------------
extern "C" void kernel_launch(void* const* d_in, const int* in_sizes, int n_in,
                              void* d_out, int out_size, void* d_ws, size_t ws_size,
                              hipStream_t stream) {
  const float* query = (const float*)d_in[0];
  const float* key   = (const float*)d_in[1];
  const float* value = (const float*)d_in[2];
  const void*  mask  = d_in[3];
  const float* wq = (const float*)d_in[4];
  const float* bq = (const float*)d_in[5];
  const float* wk = (const float*)d_in[6];
  const float* bk = (const float*)d_in[7];
  const float* wv = (const float*)d_in[8];
  const float* bv = (const float*)d_in[9];
  const float* wo = (const float*)d_in[10];
  const float* bo = (const float*)d_in[11];
  const float* lng = (const float*)d_in[12];
  const float* lnb = (const float*)d_in[13];
  float* out = (float*)d_out;

  char* ws = (char*)d_ws;
  unsigned int* flags = (unsigned int*)ws;              // 4 B
  float* Lp  = (float*)(ws + (4u << 10));               // 512 KB [4KB,516KB)
  float* Mp  = (float*)(ws + (516u << 10));             // 512 KB [516KB,1028KB)
  short* xln = (short*)(ws + (2u << 20));               // 2 MB
  short* qb  = (short*)(ws + (4u << 20));               // 2 MB
  short* kb  = (short*)(ws + (6u << 20));               // 8 MB
  short* vbT = (short*)(ws + (14u << 20));              // 8 MB [b][d][s]
  u64*   mwd = (u64*)(ws + (22u << 20));                // 2 MB
  short* w16 = (short*)(ws + (24u << 20));              // 512 KB
  char*  pool = ws + (25u << 20);                       // 18 MB, time-shared:
  short* kb16 = (short*)pool;                           //   bf16(key)   [dead after k-proj]
  short* vb16 = (short*)(pool + (8u << 20));            //   bf16(value) [dead after v-proj]
  float* Op = (float*)pool;                             //   16 MB partial O [after v-proj]
  short* ao = (short*)(pool + (16u << 20));             //   2 MB

  const float qscale = (float)(1.4426950408889634 / sqrt((double)HD));

  detect_kernel<<<1, 1024, 0, stream>>>((const uint4v*)mask, flags);
  cvt_kernel<<<2048, 256, 0, stream>>>(key, value, wq, wk, wv, wo, kb16, vb16, w16);
  maskbits_kernel<<<(BQ * QL) / 4, 256, 0, stream>>>(mask, flags, mwd);
  ln_q_kernel<<<(BQ * QL) / 4, 256, 0, stream>>>(query, lng, lnb, xln);
  gemm_bt<0><<<dim3((BQ * QL) / 64, DM / 64), 256, 0, stream>>>(xln, w16, bq, qb, nullptr, qscale);
  gemm_bt<1><<<dim3((BQ * SL) / 64, DM / 64), 256, 0, stream>>>(kb16, w16 + 65536, bk, kb, nullptr, 1.0f);
  gemm_bt<3><<<dim3((BQ * SL) / 64, DM / 64), 256, 0, stream>>>(vb16, w16 + 131072, bv, vbT, nullptr, 1.0f);
  attn_kernel<<<2048, 256, 0, stream>>>(qb, kb, vbT, mwd, Op, Lp, Mp);
  combine_kernel<<<1024, 256, 0, stream>>>(Op, Lp, Mp, ao);
  gemm_bt<2><<<dim3((BQ * QL) / 64, DM / 64), 256, 0, stream>>>(ao, w16 + 196608, bo, out, query, 1.0f);
}